// Round 5
// baseline (218.100 us; speedup 1.0000x reference)
//
#include <hip/hip_runtime.h>
#include <math.h>

using f32x4   = __attribute__((ext_vector_type(4))) float;
using bf16x8  = __attribute__((ext_vector_type(8))) short;

constexpr int Bb = 2;
constexpr int T  = 2048;
constexpr int D  = 768;
constexpr int H  = 12;
constexpr int Dh = 64;
constexpr int M  = Bb * T;        // 4096
constexpr int NQKV = 3 * D;       // 2304
// fold 1/sqrt(Dh) * log2(e) into Q so attention uses exp2 directly
#define SCALE_Q 0.18033688011112042f

// ---------------------------------------------------------------------------
// helpers
// ---------------------------------------------------------------------------
__device__ __forceinline__ unsigned short f2bf(float f) {
    unsigned u = __float_as_uint(f);
    u += 0x7fffu + ((u >> 16) & 1u);      // RNE
    return (unsigned short)(u >> 16);
}

__device__ __forceinline__ ushort4 f2bf4(float4 f) {
    return make_ushort4(f2bf(f.x), f2bf(f.y), f2bf(f.z), f2bf(f.w));
}

// truncate-pack two fp32 -> packed bf16x2 in ONE v_perm_b32:
// result = { hi16(hi_f), hi16(lo_f) }
__device__ __forceinline__ unsigned permpk(float hi_f, float lo_f) {
    return __builtin_amdgcn_perm(__float_as_uint(hi_f), __float_as_uint(lo_f),
                                 0x07060302u);
}

// async global->LDS, 16B per lane; lds base must be wave-uniform (HW scatters
// lane l's data to base + l*16)
__device__ __forceinline__ void async_copy16(const void* g, void* lds_base) {
    __builtin_amdgcn_global_load_lds(
        (const __attribute__((address_space(1))) unsigned int*)g,
        (__attribute__((address_space(3))) unsigned int*)lds_base, 16, 0, 0);
}

// ---------------------------------------------------------------------------
// Prep: fp32 -> bf16 for X, stacked Wqkv, Wo; stack biases (fp32)
// ---------------------------------------------------------------------------
__global__ __launch_bounds__(256) void prep_kernel(
    const float4* __restrict__ x,
    const float4* __restrict__ Wq, const float4* __restrict__ Wk,
    const float4* __restrict__ Wv, const float4* __restrict__ Wo,
    const float* __restrict__ bq, const float* __restrict__ bk, const float* __restrict__ bv,
    ushort4* __restrict__ Xb, ushort4* __restrict__ Wqkvb, ushort4* __restrict__ Wob,
    float* __restrict__ biasS)
{
    const int stride = gridDim.x * 256;
    const int i0 = blockIdx.x * 256 + threadIdx.x;
    const int NX = M * D / 4;       // 786432
    const int NW = D * D / 4;       // 147456
    for (int i = i0; i < NX; i += stride) Xb[i] = f2bf4(x[i]);
    for (int i = i0; i < NW; i += stride) {
        Wqkvb[i]          = f2bf4(Wq[i]);
        Wqkvb[NW + i]     = f2bf4(Wk[i]);
        Wqkvb[2 * NW + i] = f2bf4(Wv[i]);
        Wob[i]            = f2bf4(Wo[i]);
    }
    for (int i = i0; i < D; i += stride) {
        biasS[i]         = bq[i];
        biasS[D + i]     = bk[i];
        biasS[2 * D + i] = bv[i];
    }
}

// ---------------------------------------------------------------------------
// bf16 GEMM (B^T layout): C[m,n] = sum_k A[m,k] * B[n,k] + bias[n]
// TM x 128 tile, BK=64 (128 B rows = 8 x 16B blocks), 256 threads (4 waves),
// 16x16x32 MFMA. LDS rows XOR-swizzled (slot = blk ^ (row&7)) -> fragment
// ds_read_b128 are conflict-free.
// Staging: LDS = A rows [0,TM) then B rows [TM,TM+128), 1 KB chunks
// (8 rows x 128 B) round-robined over waves (wave-uniform bases).
// XCD-locality swizzle: groups of 8 consecutive linear block IDs share the
// same col-tile. (gridDim.y must be a multiple of 8.)
// MODE 0: fp32 out [M, Ndim] row-major
// MODE 1: QKV epilogue -> bf16 Q,K head-split [B,H,T,Dh] (Q pre-scaled by
//         SCALE_Q); V written TRANSPOSED [B,H,Dh,T] with keys permuted per
//         32-key group (key h*16+g*4+r -> slot g*8+h*4+r) to match the attn
//         PV MFMA k-slot order.
// ---------------------------------------------------------------------------
template <int MODE, int TM>
__global__ __launch_bounds__(256) void gemm_bt_kernel(
    const unsigned short* __restrict__ A, const unsigned short* __restrict__ Bm,
    const float* __restrict__ bias, const int Kdim, const int Ndim,
    float* __restrict__ Cout,
    unsigned short* __restrict__ Qo, unsigned short* __restrict__ Ko,
    unsigned short* __restrict__ Vo)
{
    constexpr int IW  = TM / 32;           // acc row-frags per wave
    constexpr int NCH = (TM + 128) / 8;    // 1 KB staging chunks (8 rows each)
    __shared__ unsigned short Sm[(TM + 128) * 64];
    const int tid  = threadIdx.x;
    const int lane = tid & 63, wv = tid >> 6;
    const int l15  = lane & 15, l4 = lane >> 4;
    const int wr   = wv >> 1,  wc = wv & 1;

    // swizzle (gridDim.y must be a multiple of 8)
    const int lin = blockIdx.y * gridDim.x + blockIdx.x;
    const int gx  = (lin >> 3) % gridDim.x;
    const int gy  = (lin / (8 * gridDim.x)) * 8 + (lin & 7);
    const int row0 = gy * TM, col0 = gx * 128;

    f32x4 acc[IW][4];
    #pragma unroll
    for (int i = 0; i < IW; ++i)
        #pragma unroll
        for (int j = 0; j < 4; ++j)
            acc[i][j] = (f32x4){0.f, 0.f, 0.f, 0.f};

    for (int k0 = 0; k0 < Kdim; k0 += 64) {
        __syncthreads();                       // prev iter's ds_reads done
        #pragma unroll
        for (int ch0 = 0; ch0 < NCH; ch0 += 4) {   // NCH % 4 == 0
            const int ch = ch0 + wv;           // wave-uniform per call
            const int offb = ch * 1024;
            const int off  = offb + lane * 16;
            const int r  = off >> 7;           // row in [0, TM+128)
            const int bl = (off & 127) >> 4;   // 16B block within 128 B row
            const int gc = (bl ^ (r & 7)) << 3;    // swizzled element col
            const unsigned short* src = (r < TM)
                ? A  + (size_t)(row0 + r) * Kdim + k0 + gc
                : Bm + (size_t)(col0 + (r - TM)) * Kdim + k0 + gc;
            async_copy16(src, (char*)Sm + offb);
        }
        __syncthreads();                       // drains vmcnt -> tiles ready

        #pragma unroll
        for (int c = 0; c < 2; ++c) {          // k halves of the 64-wide tile
            bf16x8 af[IW], bfr[4];
            #pragma unroll
            for (int i = 0; i < IW; ++i) {
                const int row = wr * (TM / 2) + i * 16 + l15;
                af[i] = *(const bf16x8*)((const char*)Sm +
                        row * 128 + (((c << 2) + l4) ^ (row & 7)) * 16);
            }
            #pragma unroll
            for (int j = 0; j < 4; ++j) {
                const int row = TM + wc * 64 + j * 16 + l15;
                bfr[j] = *(const bf16x8*)((const char*)Sm +
                        row * 128 + (((c << 2) + l4) ^ (row & 7)) * 16);
            }
            #pragma unroll
            for (int i = 0; i < IW; ++i)
                #pragma unroll
                for (int j = 0; j < 4; ++j)
                    acc[i][j] = __builtin_amdgcn_mfma_f32_16x16x32_bf16(af[i], bfr[j], acc[i][j], 0, 0, 0);
        }
    }

    // C/D layout: col = lane&15, row = (lane>>4)*4 + reg
    if (MODE == 0) {
        #pragma unroll
        for (int j = 0; j < 4; ++j) {
            const int n = col0 + wc * 64 + j * 16 + l15;
            const float bv_ = bias[n];
            #pragma unroll
            for (int i = 0; i < IW; ++i) {
                #pragma unroll
                for (int r = 0; r < 4; ++r) {
                    const int m = row0 + wr * (TM / 2) + i * 16 + l4 * 4 + r;
                    Cout[(size_t)m * Ndim + n] = acc[i][j][r] + bv_;
                }
            }
        }
    } else {
        #pragma unroll
        for (int j = 0; j < 4; ++j) {
            const int n = col0 + wc * 64 + j * 16 + l15;
            const int which = n / D;           // uniform per block (768 % 128 == 0)
            const int hd = n % D;
            const int h = hd >> 6, d = hd & 63;
            const float bv_ = bias[n];
            if (which == 2) {
                // V transposed [B,H,Dh,T], keys slot-permuted per 32-group:
                // t = h16*16 + g*4 + r  ->  tp = base32 | g*8 + h16*4 + r
                #pragma unroll
                for (int i = 0; i < IW; ++i) {
                    const int m0 = row0 + wr * (TM / 2) + i * 16 + l4 * 4;
                    const int b = m0 >> 11, t = m0 & (T - 1);
                    const int g = (t >> 2) & 3, h16 = (t >> 4) & 1;
                    const int tp = (t & ~31) | (g << 3) | (h16 << 2);
                    float4 v4;
                    v4.x = acc[i][j][0] + bv_; v4.y = acc[i][j][1] + bv_;
                    v4.z = acc[i][j][2] + bv_; v4.w = acc[i][j][3] + bv_;
                    *(ushort4*)&Vo[((size_t)(b * H + h) * Dh + d) * T + tp] = f2bf4(v4);
                }
            } else {
                const float scale = (which == 0) ? SCALE_Q : 1.0f;
                unsigned short* dst = (which == 0) ? Qo : Ko;
                #pragma unroll
                for (int i = 0; i < IW; ++i) {
                    #pragma unroll
                    for (int r = 0; r < 4; ++r) {
                        const int m = row0 + wr * (TM / 2) + i * 16 + l4 * 4 + r;
                        const int b = m >> 11, t = m & (T - 1);
                        dst[((size_t)(b * H + h) * T + t) * Dh + d] =
                            f2bf((acc[i][j][r] + bv_) * scale);
                    }
                }
            }
        }
    }
}

// ---------------------------------------------------------------------------
// Flash attention — proven structure (QBLK=64, 768 blocks, 1 barrier/iter).
// K is read from global into REGISTERS one tile AHEAD (T14 issue-early /
// consume-late): the 8 K fragment loads for tile t+1 are issued right after
// tile t's barrier, alongside the V staging issue, and consumed only after
// the NEXT barrier -- whose existing vmcnt(0) drain guarantees arrival. This
// fixes round-4's regression (K loads issued after the V global_load_lds and
// consumed immediately; vmcnt retires in issue order, so each K wait drained
// the in-flight next-tile V staging and serialized the pipeline -> 104 us).
// Fragment bytes are identical to round 4 (which PASSED correctness).
// Benefits vs the proven LDS-K kernel: LDS reads per wave-tile halve
// (16 -> 8 ds_read_b128), staging volume halves, grid stays 768 (3/CU).
// V keeps the proven LDS + XOR-swizzle path. Ping-pong K register buffers
// via a hand-unrolled 2x loop (all static indexing).
// ---------------------------------------------------------------------------
__global__ __launch_bounds__(256) void attn_kernel(
    const unsigned short* __restrict__ Q, const unsigned short* __restrict__ Kg,
    const unsigned short* __restrict__ Vt, unsigned short* __restrict__ Ctx)
{
    __shared__ unsigned short Vs[2][64 * 64];
    const int bh = blockIdx.y;
    const int q0 = blockIdx.x * 64;
    const int tid = threadIdx.x, lane = tid & 63, wv = tid >> 6;
    const int l15 = lane & 15, l4 = lane >> 4;
    const unsigned short* Qp = Q  + (size_t)bh * T * Dh;
    const unsigned short* Kp = Kg + (size_t)bh * T * Dh;
    const unsigned short* Vp = Vt + (size_t)bh * Dh * T;
    // per-lane K base: row part l15, k part l4*8 (chunk c adds c*32)
    const unsigned short* Kq = Kp + l15 * Dh + l4 * 8;

    // Q fragments: [n=q=l15][k = l4*8 + j], chunk c covers dh c*32..+31
    bf16x8 qf[2];
    #pragma unroll
    for (int c = 0; c < 2; ++c)
        qf[c] = *(const bf16x8*)&Qp[(size_t)(q0 + wv * 16 + l15) * Dh + c * 32 + l4 * 8];

    const short oneb = (short)0x3F80;     // bf16 1.0
    const bf16x8 onesf = {oneb, oneb, oneb, oneb, oneb, oneb, oneb, oneb};

    auto load_tiles = [&](int kt, int buf) {
        #pragma unroll
        for (int i = 0; i < 2; ++i) {
            const int offb = wv * 2048 + i * 1024;
            const int off  = offb + lane * 16;
            const int r = off >> 7;                     // 128 B per row
            const int blk = (off & 127) >> 4;
            const int gc = (blk ^ (r & 7)) << 3;        // swizzled element col
            async_copy16(Vp + (size_t)r * T + kt + gc,    (char*)&Vs[buf][0] + offb);
        }
    };

    // K register prefetch: kf[c*4 + t] = K[kt + t*16 + l15][c*32 + l4*8 ..+7]
    auto kload = [&](int kt, bf16x8 (&kf)[8]) {
        const unsigned short* Kt = Kq + (size_t)kt * Dh;
        #pragma unroll
        for (int c = 0; c < 2; ++c)
            #pragma unroll
            for (int t = 0; t < 4; ++t)
                kf[c * 4 + t] = *(const bf16x8*)(Kt + (t * 16) * Dh + c * 32);
    };

    f32x4 o[4], oL;
    #pragma unroll
    for (int nj = 0; nj < 4; ++nj) o[nj] = (f32x4){0.f, 0.f, 0.f, 0.f};
    oL = (f32x4){0.f, 0.f, 0.f, 0.f};

    bf16x8 k0[8], k1[8];
    load_tiles(0, 0);
    kload(0, k0);

    // one K-tile step: consume kf, prefetch K(t+1) into kn, V via LDS dbuf
    auto body = [&](int kt64, bf16x8 (&kf)[8], bf16x8 (&kn)[8]) {
        const int cur = kt64 & 1;
        __syncthreads();     // V(kt64)+K regs ready (vmcnt drain); buf cur^1 reads done
        if (kt64 + 1 < T / 64) {
            load_tiles((kt64 + 1) * 64, cur ^ 1);
            kload((kt64 + 1) * 64, kn);
        }

        const char* Vb = (const char*)&Vs[cur][0];

        // ---- S^T for k16 tiles 0,1 (keys 0..31), K from registers ----
        f32x4 Sa[2] = {(f32x4){0.f,0.f,0.f,0.f}, (f32x4){0.f,0.f,0.f,0.f}};
        #pragma unroll
        for (int c = 0; c < 2; ++c)
            #pragma unroll
            for (int t = 0; t < 2; ++t)
                Sa[t] = __builtin_amdgcn_mfma_f32_16x16x32_bf16(kf[c * 4 + t], qf[c], Sa[t], 0, 0, 0);
        #pragma unroll
        for (int t = 0; t < 2; ++t)
            #pragma unroll
            for (int r = 0; r < 4; ++r)
                Sa[t][r] = __builtin_amdgcn_exp2f(Sa[t][r]);
        union { unsigned u[4]; bf16x8 v; } p0;
        p0.u[0] = permpk(Sa[0][1], Sa[0][0]);
        p0.u[1] = permpk(Sa[0][3], Sa[0][2]);
        p0.u[2] = permpk(Sa[1][1], Sa[1][0]);
        p0.u[3] = permpk(Sa[1][3], Sa[1][2]);

        // ---- S^T for k16 tiles 2,3 (keys 32..63) ----
        f32x4 Sb[2] = {(f32x4){0.f,0.f,0.f,0.f}, (f32x4){0.f,0.f,0.f,0.f}};
        #pragma unroll
        for (int c = 0; c < 2; ++c)
            #pragma unroll
            for (int t = 0; t < 2; ++t)
                Sb[t] = __builtin_amdgcn_mfma_f32_16x16x32_bf16(kf[c * 4 + 2 + t], qf[c], Sb[t], 0, 0, 0);

        // ---- PV G0 (overlaps exp2 G1) ----
        oL = __builtin_amdgcn_mfma_f32_16x16x32_bf16(p0.v, onesf, oL, 0, 0, 0);
        #pragma unroll
        for (int nj = 0; nj < 4; ++nj) {
            const int row = nj * 16 + l15;
            bf16x8 vb = *(const bf16x8*)(Vb + row * 128 + ((l4) ^ (row & 7)) * 16);
            o[nj] = __builtin_amdgcn_mfma_f32_16x16x32_bf16(p0.v, vb, o[nj], 0, 0, 0);
        }

        #pragma unroll
        for (int t = 0; t < 2; ++t)
            #pragma unroll
            for (int r = 0; r < 4; ++r)
                Sb[t][r] = __builtin_amdgcn_exp2f(Sb[t][r]);
        union { unsigned u[4]; bf16x8 v; } p1;
        p1.u[0] = permpk(Sb[0][1], Sb[0][0]);
        p1.u[1] = permpk(Sb[0][3], Sb[0][2]);
        p1.u[2] = permpk(Sb[1][1], Sb[1][0]);
        p1.u[3] = permpk(Sb[1][3], Sb[1][2]);

        // ---- PV G1 ----
        oL = __builtin_amdgcn_mfma_f32_16x16x32_bf16(p1.v, onesf, oL, 0, 0, 0);
        #pragma unroll
        for (int nj = 0; nj < 4; ++nj) {
            const int row = nj * 16 + l15;
            bf16x8 vb = *(const bf16x8*)(Vb + row * 128 + ((4 + l4) ^ (row & 7)) * 16);
            o[nj] = __builtin_amdgcn_mfma_f32_16x16x32_bf16(p1.v, vb, o[nj], 0, 0, 0);
        }
    };

    // hand ping-pong: static K-buffer indexing (no runtime-indexed reg arrays)
    for (int i = 0; i < T / 64; i += 2) {
        body(i,     k0, k1);
        body(i + 1, k1, k0);
    }

    // normalize, write ctx bf16 [B, T, D]
    const int b = bh / H, h = bh % H;
    #pragma unroll
    for (int r = 0; r < 4; ++r) {
        const float inv = 1.0f / oL[r];
        const int t = q0 + wv * 16 + l4 * 4 + r;
        #pragma unroll
        for (int nj = 0; nj < 4; ++nj) {
            const int col = h * 64 + nj * 16 + l15;
            Ctx[(size_t)(b * T + t) * D + col] = f2bf(o[nj][r] * inv);
        }
    }
}

// ---------------------------------------------------------------------------
extern "C" void kernel_launch(void* const* d_in, const int* in_sizes, int n_in,
                              void* d_out, int out_size, void* d_ws, size_t ws_size,
                              hipStream_t stream) {
    const float* x  = (const float*)d_in[0];
    const float* Wq = (const float*)d_in[1];
    const float* bq = (const float*)d_in[2];
    const float* Wk = (const float*)d_in[3];
    const float* bk = (const float*)d_in[4];
    const float* Wv = (const float*)d_in[5];
    const float* bv = (const float*)d_in[6];
    const float* Wo = (const float*)d_in[7];
    const float* bo = (const float*)d_in[8];
    float* out = (float*)d_out;

    // workspace carve-up (~34 MB total)
    char* w = (char*)d_ws;
    auto alloc = [&](size_t bytes) {
        char* p = w; w += (bytes + 255) & ~(size_t)255; return p;
    };
    unsigned short* Xb    = (unsigned short*)alloc((size_t)M * D * 2);
    unsigned short* Wqkvb = (unsigned short*)alloc((size_t)NQKV * D * 2);
    unsigned short* Wob   = (unsigned short*)alloc((size_t)D * D * 2);
    float*          biasS = (float*)alloc((size_t)NQKV * 4);
    unsigned short* Qb    = (unsigned short*)alloc((size_t)M * D * 2);
    unsigned short* Kb    = (unsigned short*)alloc((size_t)M * D * 2);
    unsigned short* Vtb   = (unsigned short*)alloc((size_t)M * D * 2);
    unsigned short* Ctxb  = (unsigned short*)alloc((size_t)M * D * 2);

    prep_kernel<<<1024, 256, 0, stream>>>(
        (const float4*)x, (const float4*)Wq, (const float4*)Wk, (const float4*)Wv,
        (const float4*)Wo, bq, bk, bv,
        (ushort4*)Xb, (ushort4*)Wqkvb, (ushort4*)Wob, biasS);

    gemm_bt_kernel<1, 128><<<dim3(NQKV / 128, M / 128), 256, 0, stream>>>(
        Xb, Wqkvb, biasS, D, NQKV, nullptr, Qb, Kb, Vtb);

    // attention: QBLK=64 -> grid (32, 24) = 768 blocks (3/CU; round-3 lesson)
    attn_kernel<<<dim3(T / 64, Bb * H), 256, 0, stream>>>(Qb, Kb, Vtb, Ctxb);

    // out-projection: TM=32 (best measured across TM=32/64/128 - occupancy
    // beats LDS intensity for this small GEMM)
    gemm_bt_kernel<0, 32><<<dim3(D / 128, M / 32), 256, 0, stream>>>(
        Ctxb, Wob, bo, D, D, out, nullptr, nullptr, nullptr);
}

// Round 6
// 156.260 us; speedup vs baseline: 1.3957x; 1.3957x over previous
//
#include <hip/hip_runtime.h>
#include <math.h>

using f32x4   = __attribute__((ext_vector_type(4))) float;
using bf16x8  = __attribute__((ext_vector_type(8))) short;

constexpr int Bb = 2;
constexpr int T  = 2048;
constexpr int D  = 768;
constexpr int H  = 12;
constexpr int Dh = 64;
constexpr int M  = Bb * T;        // 4096
constexpr int NQKV = 3 * D;       // 2304
// fold 1/sqrt(Dh) * log2(e) into Q so attention uses exp2 directly
#define SCALE_Q 0.18033688011112042f

// ---------------------------------------------------------------------------
// helpers
// ---------------------------------------------------------------------------
__device__ __forceinline__ unsigned short f2bf(float f) {
    unsigned u = __float_as_uint(f);
    u += 0x7fffu + ((u >> 16) & 1u);      // RNE
    return (unsigned short)(u >> 16);
}

__device__ __forceinline__ ushort4 f2bf4(float4 f) {
    return make_ushort4(f2bf(f.x), f2bf(f.y), f2bf(f.z), f2bf(f.w));
}

// truncate-pack two fp32 -> packed bf16x2 in ONE v_perm_b32:
// result = { hi16(hi_f), hi16(lo_f) }
__device__ __forceinline__ unsigned permpk(float hi_f, float lo_f) {
    return __builtin_amdgcn_perm(__float_as_uint(hi_f), __float_as_uint(lo_f),
                                 0x07060302u);
}

// async global->LDS, 16B per lane; lds base must be wave-uniform (HW scatters
// lane l's data to base + l*16)
__device__ __forceinline__ void async_copy16(const void* g, void* lds_base) {
    __builtin_amdgcn_global_load_lds(
        (const __attribute__((address_space(1))) unsigned int*)g,
        (__attribute__((address_space(3))) unsigned int*)lds_base, 16, 0, 0);
}

// ---------------------------------------------------------------------------
// Prep: fp32 -> bf16 for X, stacked Wqkv, Wo; stack biases (fp32)
// ---------------------------------------------------------------------------
__global__ __launch_bounds__(256) void prep_kernel(
    const float4* __restrict__ x,
    const float4* __restrict__ Wq, const float4* __restrict__ Wk,
    const float4* __restrict__ Wv, const float4* __restrict__ Wo,
    const float* __restrict__ bq, const float* __restrict__ bk, const float* __restrict__ bv,
    ushort4* __restrict__ Xb, ushort4* __restrict__ Wqkvb, ushort4* __restrict__ Wob,
    float* __restrict__ biasS)
{
    const int stride = gridDim.x * 256;
    const int i0 = blockIdx.x * 256 + threadIdx.x;
    const int NX = M * D / 4;       // 786432
    const int NW = D * D / 4;       // 147456
    for (int i = i0; i < NX; i += stride) Xb[i] = f2bf4(x[i]);
    for (int i = i0; i < NW; i += stride) {
        Wqkvb[i]          = f2bf4(Wq[i]);
        Wqkvb[NW + i]     = f2bf4(Wk[i]);
        Wqkvb[2 * NW + i] = f2bf4(Wv[i]);
        Wob[i]            = f2bf4(Wo[i]);
    }
    for (int i = i0; i < D; i += stride) {
        biasS[i]         = bq[i];
        biasS[D + i]     = bk[i];
        biasS[2 * D + i] = bv[i];
    }
}

// ---------------------------------------------------------------------------
// bf16 GEMM (B^T layout): C[m,n] = sum_k A[m,k] * B[n,k] + bias[n]
// TM x 128 tile, BK=64 (128 B rows = 8 x 16B blocks), 256 threads (4 waves),
// 16x16x32 MFMA. LDS rows XOR-swizzled (slot = blk ^ (row&7)) -> fragment
// ds_read_b128 are conflict-free.
// Staging: LDS = A rows [0,TM) then B rows [TM,TM+128), 1 KB chunks
// (8 rows x 128 B) round-robined over waves (wave-uniform bases).
// DB=0: single buffer, stage -> drain -> compute (proven QKV path, verbatim).
// DB=1: double buffer, attn-style single barrier per iter: the NEXT k-tile's
//       staging is issued right after the barrier and lands during compute
//       of the CURRENT tile (the next barrier's vmcnt(0) drain guarantees
//       arrival). Out-proj only: grid gives 3 blocks/CU, below the 40 KB
//       LDS cap of 4, so no occupancy loss; halves the exposed staging
//       latency + barrier count of this latency-bound small GEMM.
// XCD-locality swizzle: groups of 8 consecutive linear block IDs share the
// same col-tile. (gridDim.y must be a multiple of 8.)
// MODE 0: fp32 out [M, Ndim] row-major
// MODE 1: QKV epilogue -> bf16 Q,K head-split [B,H,T,Dh] (Q pre-scaled by
//         SCALE_Q); V written TRANSPOSED [B,H,Dh,T] with keys permuted per
//         32-key group (key h*16+g*4+r -> slot g*8+h*4+r) to match the attn
//         PV MFMA k-slot order.
// ---------------------------------------------------------------------------
template <int MODE, int TM, int DB>
__global__ __launch_bounds__(256) void gemm_bt_kernel(
    const unsigned short* __restrict__ A, const unsigned short* __restrict__ Bm,
    const float* __restrict__ bias, const int Kdim, const int Ndim,
    float* __restrict__ Cout,
    unsigned short* __restrict__ Qo, unsigned short* __restrict__ Ko,
    unsigned short* __restrict__ Vo)
{
    constexpr int IW  = TM / 32;           // acc row-frags per wave
    constexpr int NCH = (TM + 128) / 8;    // 1 KB staging chunks (8 rows each)
    constexpr int TB  = (TM + 128) * 128;  // bytes per LDS buffer
    __shared__ unsigned short Sm[(TM + 128) * 64 * (DB ? 2 : 1)];
    const int tid  = threadIdx.x;
    const int lane = tid & 63, wv = tid >> 6;
    const int l15  = lane & 15, l4 = lane >> 4;
    const int wr   = wv >> 1,  wc = wv & 1;

    // swizzle (gridDim.y must be a multiple of 8)
    const int lin = blockIdx.y * gridDim.x + blockIdx.x;
    const int gx  = (lin >> 3) % gridDim.x;
    const int gy  = (lin / (8 * gridDim.x)) * 8 + (lin & 7);
    const int row0 = gy * TM, col0 = gx * 128;

    auto stage = [&](int k0, int b) {
        #pragma unroll
        for (int ch0 = 0; ch0 < NCH; ch0 += 4) {   // NCH % 4 == 0
            const int ch = ch0 + wv;           // wave-uniform per call
            const int offb = ch * 1024;
            const int off  = offb + lane * 16;
            const int r  = off >> 7;           // row in [0, TM+128)
            const int bl = (off & 127) >> 4;   // 16B block within 128 B row
            const int gc = (bl ^ (r & 7)) << 3;    // swizzled element col
            const unsigned short* src = (r < TM)
                ? A  + (size_t)(row0 + r) * Kdim + k0 + gc
                : Bm + (size_t)(col0 + (r - TM)) * Kdim + k0 + gc;
            async_copy16(src, (char*)Sm + b * TB + offb);
        }
    };

    f32x4 acc[IW][4];
    #pragma unroll
    for (int i = 0; i < IW; ++i)
        #pragma unroll
        for (int j = 0; j < 4; ++j)
            acc[i][j] = (f32x4){0.f, 0.f, 0.f, 0.f};

    if (DB) stage(0, 0);

    for (int k0 = 0, it = 0; k0 < Kdim; k0 += 64, ++it) {
        const int cur = DB ? (it & 1) : 0;
        __syncthreads();                 // DB=0: prev ds_reads done.
                                         // DB=1: buf[cur] staged (vmcnt drain)
                                         //       + buf[cur^1] readers done.
        if (DB) {
            if (k0 + 64 < Kdim) stage(k0 + 64, cur ^ 1);
        } else {
            stage(k0, 0);
            __syncthreads();             // drains vmcnt -> tiles ready
        }
        const char* Sb_ = (const char*)Sm + cur * TB;

        #pragma unroll
        for (int c = 0; c < 2; ++c) {          // k halves of the 64-wide tile
            bf16x8 af[IW], bfr[4];
            #pragma unroll
            for (int i = 0; i < IW; ++i) {
                const int row = wr * (TM / 2) + i * 16 + l15;
                af[i] = *(const bf16x8*)(Sb_ +
                        row * 128 + (((c << 2) + l4) ^ (row & 7)) * 16);
            }
            #pragma unroll
            for (int j = 0; j < 4; ++j) {
                const int row = TM + wc * 64 + j * 16 + l15;
                bfr[j] = *(const bf16x8*)(Sb_ +
                        row * 128 + (((c << 2) + l4) ^ (row & 7)) * 16);
            }
            #pragma unroll
            for (int i = 0; i < IW; ++i)
                #pragma unroll
                for (int j = 0; j < 4; ++j)
                    acc[i][j] = __builtin_amdgcn_mfma_f32_16x16x32_bf16(af[i], bfr[j], acc[i][j], 0, 0, 0);
        }
    }

    // C/D layout: col = lane&15, row = (lane>>4)*4 + reg
    if (MODE == 0) {
        #pragma unroll
        for (int j = 0; j < 4; ++j) {
            const int n = col0 + wc * 64 + j * 16 + l15;
            const float bv_ = bias[n];
            #pragma unroll
            for (int i = 0; i < IW; ++i) {
                #pragma unroll
                for (int r = 0; r < 4; ++r) {
                    const int m = row0 + wr * (TM / 2) + i * 16 + l4 * 4 + r;
                    Cout[(size_t)m * Ndim + n] = acc[i][j][r] + bv_;
                }
            }
        }
    } else {
        #pragma unroll
        for (int j = 0; j < 4; ++j) {
            const int n = col0 + wc * 64 + j * 16 + l15;
            const int which = n / D;           // uniform per block (768 % 128 == 0)
            const int hd = n % D;
            const int h = hd >> 6, d = hd & 63;
            const float bv_ = bias[n];
            if (which == 2) {
                // V transposed [B,H,Dh,T], keys slot-permuted per 32-group:
                // t = h16*16 + g*4 + r  ->  tp = base32 | g*8 + h16*4 + r
                #pragma unroll
                for (int i = 0; i < IW; ++i) {
                    const int m0 = row0 + wr * (TM / 2) + i * 16 + l4 * 4;
                    const int b = m0 >> 11, t = m0 & (T - 1);
                    const int g = (t >> 2) & 3, h16 = (t >> 4) & 1;
                    const int tp = (t & ~31) | (g << 3) | (h16 << 2);
                    float4 v4;
                    v4.x = acc[i][j][0] + bv_; v4.y = acc[i][j][1] + bv_;
                    v4.z = acc[i][j][2] + bv_; v4.w = acc[i][j][3] + bv_;
                    *(ushort4*)&Vo[((size_t)(b * H + h) * Dh + d) * T + tp] = f2bf4(v4);
                }
            } else {
                const float scale = (which == 0) ? SCALE_Q : 1.0f;
                unsigned short* dst = (which == 0) ? Qo : Ko;
                #pragma unroll
                for (int i = 0; i < IW; ++i) {
                    #pragma unroll
                    for (int r = 0; r < 4; ++r) {
                        const int m = row0 + wr * (TM / 2) + i * 16 + l4 * 4 + r;
                        const int b = m >> 11, t = m & (T - 1);
                        dst[((size_t)(b * H + h) * T + t) * Dh + d] =
                            f2bf((acc[i][j][r] + bv_) * scale);
                    }
                }
            }
        }
    }
}

// ---------------------------------------------------------------------------
// Flash attention (proven 47.6 us version, verbatim).
// Fixed-max softmax, S^T-in-register (16x16 shape), v_perm truncate-pack,
// phase-interleaved, ones-MFMA row-sum, 1 barrier/iter, K/V double-buffered
// via global_load_lds with XOR-swizzled 16B blocks.
// Failed directions (do not retry): wave K-split (R1, wrong results),
// QBLK=128 (R3, occupancy 3->1.5 blocks/CU), K-from-global per-lane
// (R4/R5, 104-108 us: 4x VMEM transaction amplification vs LDS broadcast).
// ---------------------------------------------------------------------------
__global__ __launch_bounds__(256) void attn_kernel(
    const unsigned short* __restrict__ Q, const unsigned short* __restrict__ Kg,
    const unsigned short* __restrict__ Vt, unsigned short* __restrict__ Ctx)
{
    __shared__ unsigned short Ks[2][64 * 64];
    __shared__ unsigned short Vs[2][64 * 64];
    const int bh = blockIdx.y;
    const int q0 = blockIdx.x * 64;
    const int tid = threadIdx.x, lane = tid & 63, wv = tid >> 6;
    const int l15 = lane & 15, l4 = lane >> 4;
    const unsigned short* Qp = Q  + (size_t)bh * T * Dh;
    const unsigned short* Kp = Kg + (size_t)bh * T * Dh;
    const unsigned short* Vp = Vt + (size_t)bh * Dh * T;

    // Q fragments: [n=q=l15][k = l4*8 + j], chunk c covers dh c*32..+31
    bf16x8 qf[2];
    #pragma unroll
    for (int c = 0; c < 2; ++c)
        qf[c] = *(const bf16x8*)&Qp[(size_t)(q0 + wv * 16 + l15) * Dh + c * 32 + l4 * 8];

    const short oneb = (short)0x3F80;     // bf16 1.0
    const bf16x8 onesf = {oneb, oneb, oneb, oneb, oneb, oneb, oneb, oneb};

    auto load_tiles = [&](int kt, int buf) {
        #pragma unroll
        for (int i = 0; i < 2; ++i) {
            const int offb = wv * 2048 + i * 1024;
            const int off  = offb + lane * 16;
            const int r = off >> 7;                     // 128 B per row
            const int blk = (off & 127) >> 4;
            const int gc = (blk ^ (r & 7)) << 3;        // swizzled element col
            async_copy16(Kp + (size_t)(kt + r) * Dh + gc, (char*)&Ks[buf][0] + offb);
            async_copy16(Vp + (size_t)r * T + kt + gc,    (char*)&Vs[buf][0] + offb);
        }
    };

    load_tiles(0, 0);
    f32x4 o[4], oL;
    #pragma unroll
    for (int nj = 0; nj < 4; ++nj) o[nj] = (f32x4){0.f, 0.f, 0.f, 0.f};
    oL = (f32x4){0.f, 0.f, 0.f, 0.f};

    for (int kt64 = 0; kt64 < T / 64; ++kt64) {
        const int cur = kt64 & 1;
        __syncthreads();     // K/V(kt64) ready (vmcnt drain); buf cur^1 reads done
        if (kt64 + 1 < T / 64) load_tiles((kt64 + 1) * 64, cur ^ 1);

        const char* Kb = (const char*)&Ks[cur][0];
        const char* Vb = (const char*)&Vs[cur][0];

        // ---- S^T for k16 tiles 0,1 (keys 0..31) ----
        f32x4 Sa[2] = {(f32x4){0.f,0.f,0.f,0.f}, (f32x4){0.f,0.f,0.f,0.f}};
        #pragma unroll
        for (int c = 0; c < 2; ++c) {
            #pragma unroll
            for (int t = 0; t < 2; ++t) {
                const int row = t * 16 + l15;
                bf16x8 kb = *(const bf16x8*)(Kb + row * 128 + (((c << 2) + l4) ^ (row & 7)) * 16);
                Sa[t] = __builtin_amdgcn_mfma_f32_16x16x32_bf16(kb, qf[c], Sa[t], 0, 0, 0);
            }
        }
        #pragma unroll
        for (int t = 0; t < 2; ++t)
            #pragma unroll
            for (int r = 0; r < 4; ++r)
                Sa[t][r] = __builtin_amdgcn_exp2f(Sa[t][r]);
        union { unsigned u[4]; bf16x8 v; } p0;
        p0.u[0] = permpk(Sa[0][1], Sa[0][0]);
        p0.u[1] = permpk(Sa[0][3], Sa[0][2]);
        p0.u[2] = permpk(Sa[1][1], Sa[1][0]);
        p0.u[3] = permpk(Sa[1][3], Sa[1][2]);

        // ---- S^T for k16 tiles 2,3 (keys 32..63) ----
        f32x4 Sb[2] = {(f32x4){0.f,0.f,0.f,0.f}, (f32x4){0.f,0.f,0.f,0.f}};
        #pragma unroll
        for (int c = 0; c < 2; ++c) {
            #pragma unroll
            for (int t = 0; t < 2; ++t) {
                const int row = (t + 2) * 16 + l15;
                bf16x8 kb = *(const bf16x8*)(Kb + row * 128 + (((c << 2) + l4) ^ (row & 7)) * 16);
                Sb[t] = __builtin_amdgcn_mfma_f32_16x16x32_bf16(kb, qf[c], Sb[t], 0, 0, 0);
            }
        }

        // ---- PV G0 (overlaps exp2 G1) ----
        oL = __builtin_amdgcn_mfma_f32_16x16x32_bf16(p0.v, onesf, oL, 0, 0, 0);
        #pragma unroll
        for (int nj = 0; nj < 4; ++nj) {
            const int row = nj * 16 + l15;
            bf16x8 vb = *(const bf16x8*)(Vb + row * 128 + ((l4) ^ (row & 7)) * 16);
            o[nj] = __builtin_amdgcn_mfma_f32_16x16x32_bf16(p0.v, vb, o[nj], 0, 0, 0);
        }

        #pragma unroll
        for (int t = 0; t < 2; ++t)
            #pragma unroll
            for (int r = 0; r < 4; ++r)
                Sb[t][r] = __builtin_amdgcn_exp2f(Sb[t][r]);
        union { unsigned u[4]; bf16x8 v; } p1;
        p1.u[0] = permpk(Sb[0][1], Sb[0][0]);
        p1.u[1] = permpk(Sb[0][3], Sb[0][2]);
        p1.u[2] = permpk(Sb[1][1], Sb[1][0]);
        p1.u[3] = permpk(Sb[1][3], Sb[1][2]);

        // ---- PV G1 ----
        oL = __builtin_amdgcn_mfma_f32_16x16x32_bf16(p1.v, onesf, oL, 0, 0, 0);
        #pragma unroll
        for (int nj = 0; nj < 4; ++nj) {
            const int row = nj * 16 + l15;
            bf16x8 vb = *(const bf16x8*)(Vb + row * 128 + ((4 + l4) ^ (row & 7)) * 16);
            o[nj] = __builtin_amdgcn_mfma_f32_16x16x32_bf16(p1.v, vb, o[nj], 0, 0, 0);
        }
    }

    // normalize, write ctx bf16 [B, T, D]
    const int b = bh / H, h = bh % H;
    #pragma unroll
    for (int r = 0; r < 4; ++r) {
        const float inv = 1.0f / oL[r];
        const int t = q0 + wv * 16 + l4 * 4 + r;
        #pragma unroll
        for (int nj = 0; nj < 4; ++nj) {
            const int col = h * 64 + nj * 16 + l15;
            Ctx[(size_t)(b * T + t) * D + col] = f2bf(o[nj][r] * inv);
        }
    }
}

// ---------------------------------------------------------------------------
extern "C" void kernel_launch(void* const* d_in, const int* in_sizes, int n_in,
                              void* d_out, int out_size, void* d_ws, size_t ws_size,
                              hipStream_t stream) {
    const float* x  = (const float*)d_in[0];
    const float* Wq = (const float*)d_in[1];
    const float* bq = (const float*)d_in[2];
    const float* Wk = (const float*)d_in[3];
    const float* bk = (const float*)d_in[4];
    const float* Wv = (const float*)d_in[5];
    const float* bv = (const float*)d_in[6];
    const float* Wo = (const float*)d_in[7];
    const float* bo = (const float*)d_in[8];
    float* out = (float*)d_out;

    // workspace carve-up (~34 MB total)
    char* w = (char*)d_ws;
    auto alloc = [&](size_t bytes) {
        char* p = w; w += (bytes + 255) & ~(size_t)255; return p;
    };
    unsigned short* Xb    = (unsigned short*)alloc((size_t)M * D * 2);
    unsigned short* Wqkvb = (unsigned short*)alloc((size_t)NQKV * D * 2);
    unsigned short* Wob   = (unsigned short*)alloc((size_t)D * D * 2);
    float*          biasS = (float*)alloc((size_t)NQKV * 4);
    unsigned short* Qb    = (unsigned short*)alloc((size_t)M * D * 2);
    unsigned short* Kb    = (unsigned short*)alloc((size_t)M * D * 2);
    unsigned short* Vtb   = (unsigned short*)alloc((size_t)M * D * 2);
    unsigned short* Ctxb  = (unsigned short*)alloc((size_t)M * D * 2);

    prep_kernel<<<1024, 256, 0, stream>>>(
        (const float4*)x, (const float4*)Wq, (const float4*)Wk, (const float4*)Wv,
        (const float4*)Wo, bq, bk, bv,
        (ushort4*)Xb, (ushort4*)Wqkvb, (ushort4*)Wob, biasS);

    // QKV GEMM: proven single-buffer path (DB=0), grid (18, 32) = 576 blocks
    gemm_bt_kernel<1, 128, 0><<<dim3(NQKV / 128, M / 128), 256, 0, stream>>>(
        Xb, Wqkvb, biasS, D, NQKV, nullptr, Qb, Kb, Vtb);

    // attention: proven kernel, QBLK=64 -> grid (32, 24) = 768 blocks (3/CU)
    attn_kernel<<<dim3(T / 64, Bb * H), 256, 0, stream>>>(Qb, Kb, Vtb, Ctxb);

    // out-projection: TM=32 (best measured) + double-buffered staging (DB=1):
    // single barrier/iter, staging overlapped with compute; 40 KB LDS caps
    // residency at 4 blocks/CU but grid only supplies 3 -> no occupancy loss.
    gemm_bt_kernel<0, 32, 1><<<dim3(D / 128, M / 32), 256, 0, stream>>>(
        Ctxb, Wob, bo, D, D, out, nullptr, nullptr, nullptr);
}